// Round 14
// baseline (111.001 us; speedup 1.0000x reference)
//
#include <hip/hip_runtime.h>

// ---------------------------------------------------------------------------
// SwitchGLU MoE, round 14: dual-path stage1 (W staged via gl_lds, X direct
// global->register). Tests whether the measured ~5.5 TB/s staging ceiling is
// LDS-DMA-path-specific (win: paths overlap, stage1 ~32us) or shared
// CU-ingress (null: ~54us). Staged bytes halve: 295 -> 147 MB.
// Stage2 / cvtx / dispatch unchanged from R13 (one variable per round).
// ---------------------------------------------------------------------------

typedef unsigned short u16;
typedef unsigned int   u32;
typedef u16    u16x8 __attribute__((ext_vector_type(8)));
typedef __bf16 bf16x8 __attribute__((ext_vector_type(8)));
typedef float  f32x4 __attribute__((ext_vector_type(4)));

#define NE   8
#define DDIM 768
#define HDIM 2048
#define NTOT 2048
#define NTOK 1024
#define MAXT1 16   // 256-row tiles
#define MAXT2 24   // 128-row tiles

__device__ __forceinline__ u16 f2bf(float f) {
  return (u16)((__builtin_bit_cast(u32, f) + 0x8000u) >> 16);
}
__device__ __forceinline__ bf16x8 cvt8(float4 a, float4 b) {
  bf16x8 r;
  r[0] = (__bf16)a.x; r[1] = (__bf16)a.y; r[2] = (__bf16)a.z; r[3] = (__bf16)a.w;
  r[4] = (__bf16)b.x; r[5] = (__bf16)b.y; r[6] = (__bf16)b.z; r[7] = (__bf16)b.w;
  return r;
}
__device__ __forceinline__ bf16x8 ldg8(const u16* p) {
  return __builtin_bit_cast(bf16x8, *reinterpret_cast<const u16x8*>(p));
}
__device__ __forceinline__ f32x4 mfma(bf16x8 a, bf16x8 b, f32x4 c) {
  return __builtin_amdgcn_mfma_f32_16x16x32_bf16(a, b, c, 0, 0, 0);
}
__device__ __forceinline__ void gl16(const void* g, void* l) {
  __builtin_amdgcn_global_load_lds(
      (const __attribute__((address_space(1))) void*)g,
      (__attribute__((address_space(3))) void*)l, 16, 0, 0);
}
#define SCHEDB() __builtin_amdgcn_sched_barrier(0)
#define BAR()    __builtin_amdgcn_s_barrier()
#define VMW(n)   asm volatile("s_waitcnt vmcnt(" #n ")" ::: "memory")
#define PSYNC()  do { SCHEDB(); \
    asm volatile("s_waitcnt vmcnt(0) lgkmcnt(0)" ::: "memory"); \
    BAR(); SCHEDB(); } while (0)

// fp32 tile frag read (R5-verified pair): rows of 32 floats, 16B chunk ^= r&7
#define RD8(arr, o_, r_, kb_) cvt8(                                              \
    *(const float4*)&(arr)[(o_) + (r_) * 32 + ((((kb_)*2    ) ^ ((r_)&7)) << 2)], \
    *(const float4*)&(arr)[(o_) + (r_) * 32 + ((((kb_)*2 + 1) ^ ((r_)&7)) << 2)])
// bf16 tile frag read (R5-verified pair): rows of 32 u16, 16B chunk ^= (r>>1)&3
#define RDB(arr, o_, r_, kb_) __builtin_bit_cast(bf16x8,                         \
    *(const u16x8*)&(arr)[(o_) + (r_) * 32 + (((kb_) ^ (((r_)>>1)&3)) << 3)])

// ---------------------------------------------------------------------------
__global__ __launch_bounds__(256) void moe_cvtx(const float* __restrict__ x,
                                                u16* __restrict__ xb) {
  const int i = (blockIdx.x * 256 + threadIdx.x) * 8;
  const float4 f0 = *(const float4*)(x + i);
  const float4 f1 = *(const float4*)(x + i + 4);
  *(uint4*)(xb + i) = __builtin_bit_cast(uint4, cvt8(f0, f1));
}

// ---------------------------------------------------------------------------
// Dispatch: expert bucketing + two tile tables (256-row and 128-row).
// meta: [0..8] offs, [14] ntiles128, [15] ntiles256,
//       [16+t] e256, [32+t] r0_256 (t<16), [48+t] e128, [80+t] r0_128 (t<24).
// ---------------------------------------------------------------------------
__global__ void moe_dispatch(const int* __restrict__ idx,
                             int* __restrict__ meta, int* __restrict__ perm) {
  __shared__ int s_cnt[NE];
  __shared__ int s_off[NE + 1];
  __shared__ int s_cur[NE];
  const int tid = threadIdx.x;
  if (tid < NE) { s_cnt[tid] = 0; s_cur[tid] = 0; }
  __syncthreads();
  for (int n = tid; n < NTOT; n += 256) atomicAdd(&s_cnt[idx[n]], 1);
  __syncthreads();
  if (tid == 0) {
    int a = 0;
    for (int e = 0; e < NE; ++e) { s_off[e] = a; a += s_cnt[e]; }
    s_off[NE] = a;
  }
  __syncthreads();
  for (int n = tid; n < NTOT; n += 256) {
    const int e = idx[n];
    perm[s_off[e] + atomicAdd(&s_cur[e], 1)] = n;
  }
  if (tid == 0) {
    int t1 = 0, t2 = 0;
    for (int e = 0; e < NE; ++e) {
      for (int r0 = s_off[e]; r0 < s_off[e + 1]; r0 += 256) {
        meta[16 + t1] = e; meta[32 + t1] = r0; ++t1;
      }
      for (int r0 = s_off[e]; r0 < s_off[e + 1]; r0 += 128) {
        meta[48 + t2] = e; meta[80 + t2] = r0; ++t2;
      }
    }
    meta[15] = t1;
    meta[14] = t2;
  }
  if (tid < NE + 1) meta[tid] = s_off[tid];
}

// ---------------------------------------------------------------------------
// Stage 1: h = silu(X Wg^T) * (X Wu^T).  BM=256, BN=64(G)+64(U), BK=32.
// grid = MAXT1*32. 512 thr = 8 waves (4M x 2N); wave = 64M x 32N of both.
// W: gl_lds ring-2 (32KB LDS total). X: direct global->reg A-frags (xb is
// 1.5MB, L2-resident on every XCD). Staged bytes/block/step: 16KB (W only).
// ---------------------------------------------------------------------------
__global__ __launch_bounds__(512, 4) void moe_stage1(
    const u16* __restrict__ xb, const int* __restrict__ perm,
    const int* __restrict__ meta, const float* __restrict__ wg,
    const float* __restrict__ wu, u16* __restrict__ hbuf) {
  const int t = blockIdx.x >> 5;
  if (t >= meta[15]) return;
  const int nt = blockIdx.x & 31;  // H cols nt*64
  const int e = meta[16 + t];
  const int r0 = meta[32 + t];
  const int rows = min(256, meta[e + 1] - r0);

  __shared__ __align__(16) float sG[2 * 64 * 32];  // 8KB/buf
  __shared__ __align__(16) float sU[2 * 64 * 32];  // 8KB/buf

  const int tid = threadIdx.x;
  const int lane = tid & 63;
  const int wv = tid >> 6;
  const int wm = (wv >> 1) * 64;  // 0,64,128,192
  const int wn = (wv & 1) * 32;   // 0,32
  const int fr = lane & 15, kb = lane >> 4;

  // X: direct per-wave A-frag pointers; lane (fr,kb) -> row fr, k kb*8..+7
  const u16* apX[4];
#pragma unroll
  for (int mi = 0; mi < 4; ++mi) {
    const int r = min(wm + mi * 16 + fr, rows - 1);
    apX[mi] = xb + (size_t)(perm[r0 + r] >> 1) * DDIM + kb * 8;  // TOPK=2
  }

  // W staging (fp32): 1 gl16/thread each; row tid>>3, chunk (tid&7)^(row&7)
  const int wr = tid >> 3;  // 0..63
  const float* gpG =
      wg + ((size_t)e * HDIM + nt * 64 + wr) * DDIM + (((tid & 7) ^ (wr & 7)) << 2);
  const float* gpU =
      wu + ((size_t)e * HDIM + nt * 64 + wr) * DDIM + (((tid & 7) ^ (wr & 7)) << 2);
  const int lbW = wv * 256;  // float units

  f32x4 aG[4][2] = {};
  f32x4 aU[4][2] = {};

#define S1_STAGE(b, kt) do {                                      \
    gl16(gpG + (kt) * 32, &sG[(b) * 2048 + lbW]);                 \
    gl16(gpU + (kt) * 32, &sU[(b) * 2048 + lbW]);                 \
  } while (0)

#define S1_COMPUTE(b, kt) do {                                    \
    const bf16x8 a0 = ldg8(apX[0] + (kt) * 32);                   \
    const bf16x8 a1 = ldg8(apX[1] + (kt) * 32);                   \
    const bf16x8 a2 = ldg8(apX[2] + (kt) * 32);                   \
    const bf16x8 a3 = ldg8(apX[3] + (kt) * 32);                   \
    bf16x8 g0 = RD8(sG, (b) * 2048, wn + fr, kb);                 \
    bf16x8 g1 = RD8(sG, (b) * 2048, wn + 16 + fr, kb);            \
    bf16x8 u0 = RD8(sU, (b) * 2048, wn + fr, kb);                 \
    bf16x8 u1 = RD8(sU, (b) * 2048, wn + 16 + fr, kb);            \
    aG[0][0] = mfma(a0, g0, aG[0][0]);                            \
    aG[1][0] = mfma(a1, g0, aG[1][0]);                            \
    aG[2][0] = mfma(a2, g0, aG[2][0]);                            \
    aG[3][0] = mfma(a3, g0, aG[3][0]);                            \
    aG[0][1] = mfma(a0, g1, aG[0][1]);                            \
    aG[1][1] = mfma(a1, g1, aG[1][1]);                            \
    aG[2][1] = mfma(a2, g1, aG[2][1]);                            \
    aG[3][1] = mfma(a3, g1, aG[3][1]);                            \
    aU[0][0] = mfma(a0, u0, aU[0][0]);                            \
    aU[1][0] = mfma(a1, u0, aU[1][0]);                            \
    aU[2][0] = mfma(a2, u0, aU[2][0]);                            \
    aU[3][0] = mfma(a3, u0, aU[3][0]);                            \
    aU[0][1] = mfma(a0, u1, aU[0][1]);                            \
    aU[1][1] = mfma(a1, u1, aU[1][1]);                            \
    aU[2][1] = mfma(a2, u1, aU[2][1]);                            \
    aU[3][1] = mfma(a3, u1, aU[3][1]);                            \
  } while (0)

  S1_STAGE(0, 0);
  PSYNC();
#pragma unroll 1
  for (int kt = 0; kt < 24; ++kt) {
    const int cb = kt & 1;
    if (kt + 1 < 24) S1_STAGE(cb ^ 1, kt + 1);
    SCHEDB();
    S1_COMPUTE(cb, kt);
    PSYNC();
  }

  // epilogue: C/D layout col=lane&15, row=(lane>>4)*4+reg
  const int crow = kb * 4, ccol = fr;
#pragma unroll
  for (int mi = 0; mi < 4; ++mi) {
#pragma unroll
    for (int ri = 0; ri < 4; ++ri) {
      const int lm = wm + mi * 16 + crow + ri;
      if (lm < rows) {
        u16* hb = hbuf + (size_t)(r0 + lm) * HDIM + nt * 64 + wn;
#pragma unroll
        for (int nj = 0; nj < 2; ++nj) {
          const float gv = aG[mi][nj][ri];
          const float uv = aU[mi][nj][ri];
          const float h = gv / (1.0f + __expf(-gv)) * uv;
          hb[nj * 16 + ccol] = f2bf(h);
        }
      }
    }
  }
}

// ---------------------------------------------------------------------------
// Stage 2 (unchanged from R13): out += h Wd^T. BM=128, BN=64, BK=32, splitK=2.
// ---------------------------------------------------------------------------
__global__ __launch_bounds__(256, 3) void moe_stage2(
    const u16* __restrict__ hbuf, const int* __restrict__ perm,
    const int* __restrict__ meta, const float* __restrict__ wd,
    float* __restrict__ out) {
  const int t = blockIdx.x / 24;
  if (t >= meta[14]) return;
  const int rem = blockIdx.x - t * 24;
  const int ks = rem / 12;
  const int nt = rem - ks * 12;
  const int e = meta[48 + t];
  const int r0 = meta[80 + t];
  const int rows = min(128, meta[e + 1] - r0);

  __shared__ __align__(16) u16   sA[3 * 128 * 32];
  __shared__ __align__(16) float sB[3 * 64 * 32];

  const int tid = threadIdx.x;
  const int lane = tid & 63;
  const int wv = tid >> 6;
  const int wm = (wv >> 1) * 64;
  const int wn = (wv & 1) * 32;

  const u16* gpA[2];
  int lbA[2];
#pragma unroll
  for (int j = 0; j < 2; ++j) {
    const int r = wv * 32 + j * 16 + (lane >> 2);
    gpA[j] = hbuf + (size_t)(r0 + min(r, rows - 1)) * HDIM + ks * 1024 +
             (((lane & 3) ^ ((r >> 1) & 3)) << 3);
    lbA[j] = (wv * 32 + j * 16) * 32;
  }
  const float* gpB[2];
  int lbB[2];
#pragma unroll
  for (int j = 0; j < 2; ++j) {
    const int r = wv * 16 + j * 8 + (lane >> 3);
    gpB[j] = wd + ((size_t)e * DDIM + nt * 64 + r) * HDIM + ks * 1024 +
             (((lane & 7) ^ (r & 7)) << 2);
    lbB[j] = (wv * 16 + j * 8) * 32;
  }

  f32x4 acc[4][2] = {};

#define S2_STAGE(slot, kp) do {                                   \
    const int su_ = (slot) * 4096, sf_ = (slot) * 2048;           \
    const int ko_ = (kp) * 32;                                    \
    gl16(gpA[0] + ko_, &sA[su_ + lbA[0]]);                        \
    gl16(gpA[1] + ko_, &sA[su_ + lbA[1]]);                        \
    gl16(gpB[0] + ko_, &sB[sf_ + lbB[0]]);                        \
    gl16(gpB[1] + ko_, &sB[sf_ + lbB[1]]);                        \
  } while (0)

#define S2_COMPUTE(slot) do {                                     \
    const int su_ = (slot) * 4096, sf_ = (slot) * 2048;           \
    const int fr_ = lane & 15, kb_ = lane >> 4;                   \
    bf16x8 a0 = RDB(sA, su_, wm + fr_, kb_);                      \
    bf16x8 a1 = RDB(sA, su_, wm + 16 + fr_, kb_);                 \
    bf16x8 a2 = RDB(sA, su_, wm + 32 + fr_, kb_);                 \
    bf16x8 a3 = RDB(sA, su_, wm + 48 + fr_, kb_);                 \
    bf16x8 b0 = RD8(sB, sf_, wn + fr_, kb_);                      \
    bf16x8 b1 = RD8(sB, sf_, wn + 16 + fr_, kb_);                 \
    acc[0][0] = mfma(a0, b0, acc[0][0]);                          \
    acc[1][0] = mfma(a1, b0, acc[1][0]);                          \
    acc[2][0] = mfma(a2, b0, acc[2][0]);                          \
    acc[3][0] = mfma(a3, b0, acc[3][0]);                          \
    acc[0][1] = mfma(a0, b1, acc[0][1]);                          \
    acc[1][1] = mfma(a1, b1, acc[1][1]);                          \
    acc[2][1] = mfma(a2, b1, acc[2][1]);                          \
    acc[3][1] = mfma(a3, b1, acc[3][1]);                          \
  } while (0)

  S2_STAGE(0, 0);
  S2_STAGE(1, 1);
  VMW(4);
  BAR();

#pragma unroll 1
  for (int l = 0; l < 32; ++l) {
    if (l + 2 < 32) S2_STAGE((l + 2) % 3, l + 2);
    SCHEDB();
    S2_COMPUTE(l % 3);
    SCHEDB();
    if (l + 2 < 32) { VMW(4); BAR(); }
    else if (l == 30) { VMW(0); BAR(); }
  }

  const int crow = (lane >> 4) << 2;
  const int ccol = lane & 15;
#pragma unroll
  for (int mi = 0; mi < 4; ++mi) {
#pragma unroll
    for (int ri = 0; ri < 4; ++ri) {
      const int lm = wm + mi * 16 + crow + ri;
      if (lm < rows) {
        const int tok = perm[r0 + lm];
        float* orow = out + (size_t)tok * DDIM + nt * 64 + wn;
#pragma unroll
        for (int nj = 0; nj < 2; ++nj) {
          atomicAdd(&orow[nj * 16 + ccol], acc[mi][nj][ri]);
        }
      }
    }
  }
}

// ---------------------------------------------------------------------------
extern "C" void kernel_launch(void* const* d_in, const int* in_sizes, int n_in,
                              void* d_out, int out_size, void* d_ws, size_t ws_size,
                              hipStream_t stream) {
  const float* x  = (const float*)d_in[0];
  const int* idx  = (const int*)d_in[1];
  const float* wg = (const float*)d_in[2];
  const float* wu = (const float*)d_in[3];
  const float* wd = (const float*)d_in[4];
  float* out = (float*)d_out;

  int* iws = (int*)d_ws;
  int* meta = iws;        // layout in moe_dispatch comment
  int* perm = iws + 128;  // 2048 ints
  u16* xbuf = (u16*)((char*)d_ws + 16384);              // 1024x768 bf16
  u16* hbuf = (u16*)((char*)d_ws + 16384 + (1 << 21));  // 2048x2048 bf16

  hipMemsetAsync(d_out, 0, (size_t)out_size * sizeof(float), stream);
  moe_cvtx<<<NTOK * DDIM / 2048, 256, 0, stream>>>(x, xbuf);
  moe_dispatch<<<1, 256, 0, stream>>>(idx, meta, perm);
  moe_stage1<<<MAXT1 * 32, 512, 0, stream>>>(xbuf, perm, meta, wg, wu, hbuf);
  moe_stage2<<<MAXT2 * 24, 256, 0, stream>>>(hbuf, perm, meta, wd, out);
}

// Round 15
// 98.345 us; speedup vs baseline: 1.1287x; 1.1287x over previous
//
#include <hip/hip_runtime.h>

// ---------------------------------------------------------------------------
// SwitchGLU MoE, round 15: stage1 -> counted-ring-3 @ 16 waves/CU.
// Cross-round staging-throughput table: counted-ring3 + >=12 waves/CU (R13
// stage2) = 7.7 TB/s; drain OR low-waves = 3.9 (R13-s1 / R12). Stage1 has
// never run in the joint regime. BM=128 fits ring-3 at 2 blocks/CU:
// 24KB/buf x3 = 72KB, 512thr/8 waves -> 16 waves/CU, vmcnt(3) steady.
// Stage2 / cvtx / dispatch byte-identical to R13 (one variable per round).
// ---------------------------------------------------------------------------

typedef unsigned short u16;
typedef unsigned int   u32;
typedef u16    u16x8 __attribute__((ext_vector_type(8)));
typedef __bf16 bf16x8 __attribute__((ext_vector_type(8)));
typedef float  f32x4 __attribute__((ext_vector_type(4)));

#define NE   8
#define DDIM 768
#define HDIM 2048
#define NTOT 2048
#define NTOK 1024
#define MAXT2 24   // 128-row tiles

__device__ __forceinline__ u16 f2bf(float f) {
  return (u16)((__builtin_bit_cast(u32, f) + 0x8000u) >> 16);
}
__device__ __forceinline__ bf16x8 cvt8(float4 a, float4 b) {
  bf16x8 r;
  r[0] = (__bf16)a.x; r[1] = (__bf16)a.y; r[2] = (__bf16)a.z; r[3] = (__bf16)a.w;
  r[4] = (__bf16)b.x; r[5] = (__bf16)b.y; r[6] = (__bf16)b.z; r[7] = (__bf16)b.w;
  return r;
}
__device__ __forceinline__ f32x4 mfma(bf16x8 a, bf16x8 b, f32x4 c) {
  return __builtin_amdgcn_mfma_f32_16x16x32_bf16(a, b, c, 0, 0, 0);
}
__device__ __forceinline__ void gl16(const void* g, void* l) {
  __builtin_amdgcn_global_load_lds(
      (const __attribute__((address_space(1))) void*)g,
      (__attribute__((address_space(3))) void*)l, 16, 0, 0);
}
#define SCHEDB() __builtin_amdgcn_sched_barrier(0)
#define BAR()    __builtin_amdgcn_s_barrier()
#define VMW(n)   asm volatile("s_waitcnt vmcnt(" #n ")" ::: "memory")

// fp32 tile frag read (R5-verified pair): rows of 32 floats, 16B chunk ^= r&7
#define RD8(arr, o_, r_, kb_) cvt8(                                              \
    *(const float4*)&(arr)[(o_) + (r_) * 32 + ((((kb_)*2    ) ^ ((r_)&7)) << 2)], \
    *(const float4*)&(arr)[(o_) + (r_) * 32 + ((((kb_)*2 + 1) ^ ((r_)&7)) << 2)])
// bf16 tile frag read (R5-verified pair): rows of 32 u16, 16B chunk ^= (r>>1)&3
#define RDB(arr, o_, r_, kb_) __builtin_bit_cast(bf16x8,                         \
    *(const u16x8*)&(arr)[(o_) + (r_) * 32 + (((kb_) ^ (((r_)>>1)&3)) << 3)])

// ---------------------------------------------------------------------------
__global__ __launch_bounds__(256) void moe_cvtx(const float* __restrict__ x,
                                                u16* __restrict__ xb) {
  const int i = (blockIdx.x * 256 + threadIdx.x) * 8;
  const float4 f0 = *(const float4*)(x + i);
  const float4 f1 = *(const float4*)(x + i + 4);
  *(uint4*)(xb + i) = __builtin_bit_cast(uint4, cvt8(f0, f1));
}

// ---------------------------------------------------------------------------
// Dispatch: expert bucketing + 128-row tile table.
// meta: [0..8] offs, [14] ntiles128, [48+t] e128, [80+t] r0_128 (t<24).
// ---------------------------------------------------------------------------
__global__ void moe_dispatch(const int* __restrict__ idx,
                             int* __restrict__ meta, int* __restrict__ perm) {
  __shared__ int s_cnt[NE];
  __shared__ int s_off[NE + 1];
  __shared__ int s_cur[NE];
  const int tid = threadIdx.x;
  if (tid < NE) { s_cnt[tid] = 0; s_cur[tid] = 0; }
  __syncthreads();
  for (int n = tid; n < NTOT; n += 256) atomicAdd(&s_cnt[idx[n]], 1);
  __syncthreads();
  if (tid == 0) {
    int a = 0;
    for (int e = 0; e < NE; ++e) { s_off[e] = a; a += s_cnt[e]; }
    s_off[NE] = a;
  }
  __syncthreads();
  for (int n = tid; n < NTOT; n += 256) {
    const int e = idx[n];
    perm[s_off[e] + atomicAdd(&s_cur[e], 1)] = n;
  }
  if (tid == 0) {
    int t2 = 0;
    for (int e = 0; e < NE; ++e) {
      for (int r0 = s_off[e]; r0 < s_off[e + 1]; r0 += 128) {
        meta[48 + t2] = e; meta[80 + t2] = r0; ++t2;
      }
    }
    meta[14] = t2;
  }
  if (tid < NE + 1) meta[tid] = s_off[tid];
}

// ---------------------------------------------------------------------------
// Stage 1: h = silu(X Wg^T) * (X Wu^T).  BM=128, BN=64(G)+64(U), BK=32.
// grid = MAXT2*32 (tile t, strip nt). 512 thr = 8 waves (4M x 2N);
// wave = 32M x 32N of both. Ring-3 LDS 72KB (2 blocks/CU, 16 waves/CU).
// 3 gl_lds/thread/step; steady vmcnt(3) -> next step's loads fly across bar.
// ---------------------------------------------------------------------------
__global__ __launch_bounds__(512, 2) void moe_stage1(
    const u16* __restrict__ xb, const int* __restrict__ perm,
    const int* __restrict__ meta, const float* __restrict__ wg,
    const float* __restrict__ wu, u16* __restrict__ hbuf) {
  const int t = blockIdx.x >> 5;
  if (t >= meta[14]) return;
  const int nt = blockIdx.x & 31;  // H cols nt*64
  const int e = meta[48 + t];
  const int r0 = meta[80 + t];
  const int rows = min(128, meta[e + 1] - r0);

  __shared__ __align__(16) u16   sX[3 * 128 * 32];  // 8KB/buf
  __shared__ __align__(16) float sG[3 * 64 * 32];   // 8KB/buf
  __shared__ __align__(16) float sU[3 * 64 * 32];   // 8KB/buf

  const int tid = threadIdx.x;
  const int lane = tid & 63;
  const int wv = tid >> 6;
  const int wm = (wv >> 1) * 32;  // 0,32,64,96
  const int wn = (wv & 1) * 32;   // 0,32
  const int fr = lane & 15, kb = lane >> 4;

  // X staging (bf16): 1 gl16/thread; row tid>>2, chunk (tid&3)^((r>>1)&3)
  const int xr = tid >> 2;  // 0..127
  const int tok = perm[r0 + min(xr, rows - 1)] >> 1;  // TOPK=2
  const u16* gpX = xb + (size_t)tok * DDIM + (((tid & 3) ^ ((xr >> 1) & 3)) << 3);
  const int lbX = wv * 512;  // u16 units (16 rows/wave)
  // W staging (fp32): 1 gl16/thread each; row tid>>3, chunk (tid&7)^(row&7)
  const int wr = tid >> 3;  // 0..63
  const float* gpG =
      wg + ((size_t)e * HDIM + nt * 64 + wr) * DDIM + (((tid & 7) ^ (wr & 7)) << 2);
  const float* gpU =
      wu + ((size_t)e * HDIM + nt * 64 + wr) * DDIM + (((tid & 7) ^ (wr & 7)) << 2);
  const int lbW = wv * 256;  // float units (8 rows/wave)

  f32x4 aG[2][2] = {};
  f32x4 aU[2][2] = {};

#define S1_STAGE(slot, kt) do {                                   \
    gl16(gpX + (kt) * 32, &sX[(slot) * 4096 + lbX]);              \
    gl16(gpG + (kt) * 32, &sG[(slot) * 2048 + lbW]);              \
    gl16(gpU + (kt) * 32, &sU[(slot) * 2048 + lbW]);              \
  } while (0)

#define S1_COMPUTE(slot) do {                                     \
    const int su_ = (slot) * 4096, sf_ = (slot) * 2048;           \
    bf16x8 a0 = RDB(sX, su_, wm + fr, kb);                        \
    bf16x8 a1 = RDB(sX, su_, wm + 16 + fr, kb);                   \
    bf16x8 g0 = RD8(sG, sf_, wn + fr, kb);                        \
    bf16x8 g1 = RD8(sG, sf_, wn + 16 + fr, kb);                   \
    bf16x8 u0 = RD8(sU, sf_, wn + fr, kb);                        \
    bf16x8 u1 = RD8(sU, sf_, wn + 16 + fr, kb);                   \
    aG[0][0] = mfma(a0, g0, aG[0][0]);                            \
    aG[1][0] = mfma(a1, g0, aG[1][0]);                            \
    aG[0][1] = mfma(a0, g1, aG[0][1]);                            \
    aG[1][1] = mfma(a1, g1, aG[1][1]);                            \
    aU[0][0] = mfma(a0, u0, aU[0][0]);                            \
    aU[1][0] = mfma(a1, u0, aU[1][0]);                            \
    aU[0][1] = mfma(a0, u1, aU[0][1]);                            \
    aU[1][1] = mfma(a1, u1, aU[1][1]);                            \
  } while (0)

  S1_STAGE(0, 0);
  S1_STAGE(1, 1);
  VMW(3);   // buf0 complete; buf1's 3 still in flight
  BAR();

#pragma unroll 1
  for (int l = 0; l < 24; ++l) {
    if (l + 2 < 24) S1_STAGE((l + 2) % 3, l + 2);
    SCHEDB();
    S1_COMPUTE(l % 3);
    SCHEDB();
    if (l + 2 < 24) { VMW(3); BAR(); }
    else if (l == 22) { VMW(0); BAR(); }
  }

  // epilogue: C/D layout col=lane&15, row=(lane>>4)*4+reg
  const int crow = kb * 4, ccol = fr;
#pragma unroll
  for (int mi = 0; mi < 2; ++mi) {
#pragma unroll
    for (int ri = 0; ri < 4; ++ri) {
      const int lm = wm + mi * 16 + crow + ri;
      if (lm < rows) {
        u16* hb = hbuf + (size_t)(r0 + lm) * HDIM + nt * 64 + wn;
#pragma unroll
        for (int nj = 0; nj < 2; ++nj) {
          const float gv = aG[mi][nj][ri];
          const float uv = aU[mi][nj][ri];
          const float h = gv / (1.0f + __expf(-gv)) * uv;
          hb[nj * 16 + ccol] = f2bf(h);
        }
      }
    }
  }
}

// ---------------------------------------------------------------------------
// Stage 2 (byte-identical to R13): out += h Wd^T. BM=128/BN=64/BK=32/splitK=2.
// Ring-3 LDS 48KB (3 blocks/CU), counted vmcnt(4).
// ---------------------------------------------------------------------------
__global__ __launch_bounds__(256, 3) void moe_stage2(
    const u16* __restrict__ hbuf, const int* __restrict__ perm,
    const int* __restrict__ meta, const float* __restrict__ wd,
    float* __restrict__ out) {
  const int t = blockIdx.x / 24;
  if (t >= meta[14]) return;
  const int rem = blockIdx.x - t * 24;
  const int ks = rem / 12;
  const int nt = rem - ks * 12;
  const int e = meta[48 + t];
  const int r0 = meta[80 + t];
  const int rows = min(128, meta[e + 1] - r0);

  __shared__ __align__(16) u16   sA[3 * 128 * 32];
  __shared__ __align__(16) float sB[3 * 64 * 32];

  const int tid = threadIdx.x;
  const int lane = tid & 63;
  const int wv = tid >> 6;
  const int wm = (wv >> 1) * 64;
  const int wn = (wv & 1) * 32;

  const u16* gpA[2];
  int lbA[2];
#pragma unroll
  for (int j = 0; j < 2; ++j) {
    const int r = wv * 32 + j * 16 + (lane >> 2);
    gpA[j] = hbuf + (size_t)(r0 + min(r, rows - 1)) * HDIM + ks * 1024 +
             (((lane & 3) ^ ((r >> 1) & 3)) << 3);
    lbA[j] = (wv * 32 + j * 16) * 32;
  }
  const float* gpB[2];
  int lbB[2];
#pragma unroll
  for (int j = 0; j < 2; ++j) {
    const int r = wv * 16 + j * 8 + (lane >> 3);
    gpB[j] = wd + ((size_t)e * DDIM + nt * 64 + r) * HDIM + ks * 1024 +
             (((lane & 7) ^ (r & 7)) << 2);
    lbB[j] = (wv * 16 + j * 8) * 32;
  }

  f32x4 acc[4][2] = {};

#define S2_STAGE(slot, kp) do {                                   \
    const int su_ = (slot) * 4096, sf_ = (slot) * 2048;           \
    const int ko_ = (kp) * 32;                                    \
    gl16(gpA[0] + ko_, &sA[su_ + lbA[0]]);                        \
    gl16(gpA[1] + ko_, &sA[su_ + lbA[1]]);                        \
    gl16(gpB[0] + ko_, &sB[sf_ + lbB[0]]);                        \
    gl16(gpB[1] + ko_, &sB[sf_ + lbB[1]]);                        \
  } while (0)

#define S2_COMPUTE(slot) do {                                     \
    const int su_ = (slot) * 4096, sf_ = (slot) * 2048;           \
    const int fr_ = lane & 15, kb_ = lane >> 4;                   \
    bf16x8 a0 = RDB(sA, su_, wm + fr_, kb_);                      \
    bf16x8 a1 = RDB(sA, su_, wm + 16 + fr_, kb_);                 \
    bf16x8 a2 = RDB(sA, su_, wm + 32 + fr_, kb_);                 \
    bf16x8 a3 = RDB(sA, su_, wm + 48 + fr_, kb_);                 \
    bf16x8 b0 = RD8(sB, sf_, wn + fr_, kb_);                      \
    bf16x8 b1 = RD8(sB, sf_, wn + 16 + fr_, kb_);                 \
    acc[0][0] = mfma(a0, b0, acc[0][0]);                          \
    acc[1][0] = mfma(a1, b0, acc[1][0]);                          \
    acc[2][0] = mfma(a2, b0, acc[2][0]);                          \
    acc[3][0] = mfma(a3, b0, acc[3][0]);                          \
    acc[0][1] = mfma(a0, b1, acc[0][1]);                          \
    acc[1][1] = mfma(a1, b1, acc[1][1]);                          \
    acc[2][1] = mfma(a2, b1, acc[2][1]);                          \
    acc[3][1] = mfma(a3, b1, acc[3][1]);                          \
  } while (0)

  S2_STAGE(0, 0);
  S2_STAGE(1, 1);
  VMW(4);
  BAR();

#pragma unroll 1
  for (int l = 0; l < 32; ++l) {
    if (l + 2 < 32) S2_STAGE((l + 2) % 3, l + 2);
    SCHEDB();
    S2_COMPUTE(l % 3);
    SCHEDB();
    if (l + 2 < 32) { VMW(4); BAR(); }
    else if (l == 30) { VMW(0); BAR(); }
  }

  const int crow = (lane >> 4) << 2;
  const int ccol = lane & 15;
#pragma unroll
  for (int mi = 0; mi < 4; ++mi) {
#pragma unroll
    for (int ri = 0; ri < 4; ++ri) {
      const int lm = wm + mi * 16 + crow + ri;
      if (lm < rows) {
        const int tok = perm[r0 + lm];
        float* orow = out + (size_t)tok * DDIM + nt * 64 + wn;
#pragma unroll
        for (int nj = 0; nj < 2; ++nj) {
          atomicAdd(&orow[nj * 16 + ccol], acc[mi][nj][ri]);
        }
      }
    }
  }
}

// ---------------------------------------------------------------------------
extern "C" void kernel_launch(void* const* d_in, const int* in_sizes, int n_in,
                              void* d_out, int out_size, void* d_ws, size_t ws_size,
                              hipStream_t stream) {
  const float* x  = (const float*)d_in[0];
  const int* idx  = (const int*)d_in[1];
  const float* wg = (const float*)d_in[2];
  const float* wu = (const float*)d_in[3];
  const float* wd = (const float*)d_in[4];
  float* out = (float*)d_out;

  int* iws = (int*)d_ws;
  int* meta = iws;        // layout in moe_dispatch comment
  int* perm = iws + 128;  // 2048 ints
  u16* xbuf = (u16*)((char*)d_ws + 16384);              // 1024x768 bf16
  u16* hbuf = (u16*)((char*)d_ws + 16384 + (1 << 21));  // 2048x2048 bf16

  hipMemsetAsync(d_out, 0, (size_t)out_size * sizeof(float), stream);
  moe_cvtx<<<NTOK * DDIM / 2048, 256, 0, stream>>>(x, xbuf);
  moe_dispatch<<<1, 256, 0, stream>>>(idx, meta, perm);
  moe_stage1<<<MAXT2 * 32, 512, 0, stream>>>(xbuf, perm, meta, wg, wu, hbuf);
  moe_stage2<<<MAXT2 * 24, 256, 0, stream>>>(hbuf, perm, meta, wd, out);
}

// Round 16
// 91.082 us; speedup vs baseline: 1.2187x; 1.0797x over previous
//
#include <hip/hip_runtime.h>

// ---------------------------------------------------------------------------
// SwitchGLU MoE, round 16: restore R13 (best: 88.8us) + XCD-chunked swizzle.
// Cross-round model: staging rate = 8 TB/s iff 3 blocks/CU (indep barrier
// domains), else ~4 TB/s; stage1 can't fit 3/CU at low traffic -> both
// regimes converge ~55us. R14/R15 regressed; this restores R13 and adds the
// only zero-risk lever left: T1 XCD-chunked block swizzle (grids 512/576 are
// exact multiples of 8 -> bijective swz = (b%8)*(n/8)+b/8).
// ---------------------------------------------------------------------------

typedef unsigned short u16;
typedef unsigned int   u32;
typedef u16    u16x8 __attribute__((ext_vector_type(8)));
typedef __bf16 bf16x8 __attribute__((ext_vector_type(8)));
typedef float  f32x4 __attribute__((ext_vector_type(4)));

#define NE   8
#define DDIM 768
#define HDIM 2048
#define NTOT 2048
#define NTOK 1024
#define MAXT1 16   // 256-row tiles
#define MAXT2 24   // 128-row tiles

__device__ __forceinline__ u16 f2bf(float f) {
  return (u16)((__builtin_bit_cast(u32, f) + 0x8000u) >> 16);
}
__device__ __forceinline__ bf16x8 cvt8(float4 a, float4 b) {
  bf16x8 r;
  r[0] = (__bf16)a.x; r[1] = (__bf16)a.y; r[2] = (__bf16)a.z; r[3] = (__bf16)a.w;
  r[4] = (__bf16)b.x; r[5] = (__bf16)b.y; r[6] = (__bf16)b.z; r[7] = (__bf16)b.w;
  return r;
}
__device__ __forceinline__ f32x4 mfma(bf16x8 a, bf16x8 b, f32x4 c) {
  return __builtin_amdgcn_mfma_f32_16x16x32_bf16(a, b, c, 0, 0, 0);
}
__device__ __forceinline__ void gl16(const void* g, void* l) {
  __builtin_amdgcn_global_load_lds(
      (const __attribute__((address_space(1))) void*)g,
      (__attribute__((address_space(3))) void*)l, 16, 0, 0);
}
#define SCHEDB() __builtin_amdgcn_sched_barrier(0)
#define BAR()    __builtin_amdgcn_s_barrier()
#define VMW(n)   asm volatile("s_waitcnt vmcnt(" #n ")" ::: "memory")
#define PSYNC()  do { SCHEDB(); \
    asm volatile("s_waitcnt vmcnt(0) lgkmcnt(0)" ::: "memory"); \
    BAR(); SCHEDB(); } while (0)

// fp32 tile frag read (R5-verified pair): rows of 32 floats, 16B chunk ^= r&7
#define RD8(arr, o_, r_, kb_) cvt8(                                              \
    *(const float4*)&(arr)[(o_) + (r_) * 32 + ((((kb_)*2    ) ^ ((r_)&7)) << 2)], \
    *(const float4*)&(arr)[(o_) + (r_) * 32 + ((((kb_)*2 + 1) ^ ((r_)&7)) << 2)])
// bf16 tile frag read (R5-verified pair): rows of 32 u16, 16B chunk ^= (r>>1)&3
#define RDB(arr, o_, r_, kb_) __builtin_bit_cast(bf16x8,                         \
    *(const u16x8*)&(arr)[(o_) + (r_) * 32 + (((kb_) ^ (((r_)>>1)&3)) << 3)])

// ---------------------------------------------------------------------------
__global__ __launch_bounds__(256) void moe_cvtx(const float* __restrict__ x,
                                                u16* __restrict__ xb) {
  const int i = (blockIdx.x * 256 + threadIdx.x) * 8;
  const float4 f0 = *(const float4*)(x + i);
  const float4 f1 = *(const float4*)(x + i + 4);
  *(uint4*)(xb + i) = __builtin_bit_cast(uint4, cvt8(f0, f1));
}

// ---------------------------------------------------------------------------
// Dispatch: expert bucketing + two tile tables (256-row and 128-row).
// meta: [0..8] offs, [14] ntiles128, [15] ntiles256,
//       [16+t] e256, [32+t] r0_256 (t<16), [48+t] e128, [80+t] r0_128 (t<24).
// ---------------------------------------------------------------------------
__global__ void moe_dispatch(const int* __restrict__ idx,
                             int* __restrict__ meta, int* __restrict__ perm) {
  __shared__ int s_cnt[NE];
  __shared__ int s_off[NE + 1];
  __shared__ int s_cur[NE];
  const int tid = threadIdx.x;
  if (tid < NE) { s_cnt[tid] = 0; s_cur[tid] = 0; }
  __syncthreads();
  for (int n = tid; n < NTOT; n += 256) atomicAdd(&s_cnt[idx[n]], 1);
  __syncthreads();
  if (tid == 0) {
    int a = 0;
    for (int e = 0; e < NE; ++e) { s_off[e] = a; a += s_cnt[e]; }
    s_off[NE] = a;
  }
  __syncthreads();
  for (int n = tid; n < NTOT; n += 256) {
    const int e = idx[n];
    perm[s_off[e] + atomicAdd(&s_cur[e], 1)] = n;
  }
  if (tid == 0) {
    int t1 = 0, t2 = 0;
    for (int e = 0; e < NE; ++e) {
      for (int r0 = s_off[e]; r0 < s_off[e + 1]; r0 += 256) {
        meta[16 + t1] = e; meta[32 + t1] = r0; ++t1;
      }
      for (int r0 = s_off[e]; r0 < s_off[e + 1]; r0 += 128) {
        meta[48 + t2] = e; meta[80 + t2] = r0; ++t2;
      }
    }
    meta[15] = t1;
    meta[14] = t2;
  }
  if (tid < NE + 1) meta[tid] = s_off[tid];
}

// ---------------------------------------------------------------------------
// Stage 1: h = silu(X Wg^T) * (X Wu^T).  BM=256, BN=64(G)+64(U), BK=32.
// grid = 512 (16 tiles x 32 strips), XCD-chunked. 512 thr = 8 waves (4Mx2N);
// wave = 64M x 32N of both. Ring-2 LDS 64KB (2 blocks/CU), drain per step.
// Per-expert weights enter CUs exactly once (BM covers the whole expert).
// ---------------------------------------------------------------------------
__global__ __launch_bounds__(512, 4) void moe_stage1(
    const u16* __restrict__ xb, const int* __restrict__ perm,
    const int* __restrict__ meta, const float* __restrict__ wg,
    const float* __restrict__ wu, u16* __restrict__ hbuf) {
  // XCD-chunked bijection on grid 512: 64 consecutive logical blocks per XCD
  const int bid = (blockIdx.x & 7) * 64 + (blockIdx.x >> 3);
  const int t = bid >> 5;
  if (t >= meta[15]) return;
  const int nt = bid & 31;  // H cols nt*64
  const int e = meta[16 + t];
  const int r0 = meta[32 + t];
  const int rows = min(256, meta[e + 1] - r0);

  __shared__ __align__(16) u16   sX[2 * 256 * 32];  // 16KB/buf
  __shared__ __align__(16) float sG[2 * 64 * 32];   // 8KB/buf
  __shared__ __align__(16) float sU[2 * 64 * 32];   // 8KB/buf

  const int tid = threadIdx.x;
  const int lane = tid & 63;
  const int wv = tid >> 6;
  const int wm = (wv >> 1) * 64;  // 0,64,128,192
  const int wn = (wv & 1) * 32;   // 0,32

  // X staging (bf16): 2 gl16/thread; pair p = j*512+tid -> (row p>>2, chunk p&3)
  const u16* gpX[2];
  int lbX[2];
#pragma unroll
  for (int j = 0; j < 2; ++j) {
    const int r = j * 128 + (tid >> 2);
    const int tok = perm[r0 + min(r, rows - 1)] >> 1;  // TOPK=2
    gpX[j] = xb + (size_t)tok * DDIM + (((tid & 3) ^ ((r >> 1) & 3)) << 3);
    lbX[j] = j * 4096 + wv * 512;  // u16 units
  }
  // W staging (fp32): 1 gl16/thread each; row tid>>3, chunk (tid&7)^(row&7)
  const int wr = tid >> 3;  // 0..63
  const float* gpG =
      wg + ((size_t)e * HDIM + nt * 64 + wr) * DDIM + (((tid & 7) ^ (wr & 7)) << 2);
  const float* gpU =
      wu + ((size_t)e * HDIM + nt * 64 + wr) * DDIM + (((tid & 7) ^ (wr & 7)) << 2);
  const int lbW = wv * 256;  // float units

  f32x4 aG[4][2] = {};
  f32x4 aU[4][2] = {};

#define S1_STAGE(b, kt) do {                                      \
    gl16(gpX[0] + (kt) * 32, &sX[(b) * 8192 + lbX[0]]);           \
    gl16(gpX[1] + (kt) * 32, &sX[(b) * 8192 + lbX[1]]);           \
    gl16(gpG + (kt) * 32, &sG[(b) * 2048 + lbW]);                 \
    gl16(gpU + (kt) * 32, &sU[(b) * 2048 + lbW]);                 \
  } while (0)

#define S1_COMPUTE(b) do {                                        \
    const int fr_ = lane & 15, kb_ = lane >> 4;                   \
    bf16x8 a0 = RDB(sX, (b) * 8192, wm + fr_, kb_);               \
    bf16x8 a1 = RDB(sX, (b) * 8192, wm + 16 + fr_, kb_);          \
    bf16x8 a2 = RDB(sX, (b) * 8192, wm + 32 + fr_, kb_);          \
    bf16x8 a3 = RDB(sX, (b) * 8192, wm + 48 + fr_, kb_);          \
    bf16x8 g0 = RD8(sG, (b) * 2048, wn + fr_, kb_);               \
    bf16x8 g1 = RD8(sG, (b) * 2048, wn + 16 + fr_, kb_);          \
    bf16x8 u0 = RD8(sU, (b) * 2048, wn + fr_, kb_);               \
    bf16x8 u1 = RD8(sU, (b) * 2048, wn + 16 + fr_, kb_);          \
    aG[0][0] = mfma(a0, g0, aG[0][0]);                            \
    aG[1][0] = mfma(a1, g0, aG[1][0]);                            \
    aG[2][0] = mfma(a2, g0, aG[2][0]);                            \
    aG[3][0] = mfma(a3, g0, aG[3][0]);                            \
    aG[0][1] = mfma(a0, g1, aG[0][1]);                            \
    aG[1][1] = mfma(a1, g1, aG[1][1]);                            \
    aG[2][1] = mfma(a2, g1, aG[2][1]);                            \
    aG[3][1] = mfma(a3, g1, aG[3][1]);                            \
    aU[0][0] = mfma(a0, u0, aU[0][0]);                            \
    aU[1][0] = mfma(a1, u0, aU[1][0]);                            \
    aU[2][0] = mfma(a2, u0, aU[2][0]);                            \
    aU[3][0] = mfma(a3, u0, aU[3][0]);                            \
    aU[0][1] = mfma(a0, u1, aU[0][1]);                            \
    aU[1][1] = mfma(a1, u1, aU[1][1]);                            \
    aU[2][1] = mfma(a2, u1, aU[2][1]);                            \
    aU[3][1] = mfma(a3, u1, aU[3][1]);                            \
  } while (0)

  S1_STAGE(0, 0);
  PSYNC();
#pragma unroll 1
  for (int kt = 0; kt < 24; ++kt) {
    const int cb = kt & 1;
    if (kt + 1 < 24) S1_STAGE(cb ^ 1, kt + 1);
    SCHEDB();
    S1_COMPUTE(cb);
    PSYNC();
  }

  // epilogue: C/D layout col=lane&15, row=(lane>>4)*4+reg
  const int crow = (lane >> 4) << 2;
  const int ccol = lane & 15;
#pragma unroll
  for (int mi = 0; mi < 4; ++mi) {
#pragma unroll
    for (int ri = 0; ri < 4; ++ri) {
      const int lm = wm + mi * 16 + crow + ri;
      if (lm < rows) {
        u16* hb = hbuf + (size_t)(r0 + lm) * HDIM + nt * 64 + wn;
#pragma unroll
        for (int nj = 0; nj < 2; ++nj) {
          const float gv = aG[mi][nj][ri];
          const float uv = aU[mi][nj][ri];
          const float h = gv / (1.0f + __expf(-gv)) * uv;
          hb[nj * 16 + ccol] = f2bf(h);
        }
      }
    }
  }
}

// ---------------------------------------------------------------------------
// Stage 2: out += h Wd^T. BM=128, BN=64, BK=32, split-K=2.
// grid = 576 (24 tiles x 24), XCD-chunked (72/XCD -> same-tile blocks local).
// 256 thr = 4 waves (2M x 2N). Ring-3 LDS 48KB (3 blocks/CU), vmcnt(4).
// ---------------------------------------------------------------------------
__global__ __launch_bounds__(256, 3) void moe_stage2(
    const u16* __restrict__ hbuf, const int* __restrict__ perm,
    const int* __restrict__ meta, const float* __restrict__ wd,
    float* __restrict__ out) {
  // XCD-chunked bijection on grid 576: 72 consecutive logical blocks per XCD
  const int bid = (blockIdx.x & 7) * 72 + (blockIdx.x >> 3);
  const int t = bid / 24;
  if (t >= meta[14]) return;
  const int rem = bid - t * 24;
  const int ks = rem / 12;
  const int nt = rem - ks * 12;
  const int e = meta[48 + t];
  const int r0 = meta[80 + t];
  const int rows = min(128, meta[e + 1] - r0);

  __shared__ __align__(16) u16   sA[3 * 128 * 32];
  __shared__ __align__(16) float sB[3 * 64 * 32];

  const int tid = threadIdx.x;
  const int lane = tid & 63;
  const int wv = tid >> 6;
  const int wm = (wv >> 1) * 64;
  const int wn = (wv & 1) * 32;

  const u16* gpA[2];
  int lbA[2];
#pragma unroll
  for (int j = 0; j < 2; ++j) {
    const int r = wv * 32 + j * 16 + (lane >> 2);
    gpA[j] = hbuf + (size_t)(r0 + min(r, rows - 1)) * HDIM + ks * 1024 +
             (((lane & 3) ^ ((r >> 1) & 3)) << 3);
    lbA[j] = (wv * 32 + j * 16) * 32;
  }
  const float* gpB[2];
  int lbB[2];
#pragma unroll
  for (int j = 0; j < 2; ++j) {
    const int r = wv * 16 + j * 8 + (lane >> 3);
    gpB[j] = wd + ((size_t)e * DDIM + nt * 64 + r) * HDIM + ks * 1024 +
             (((lane & 7) ^ (r & 7)) << 2);
    lbB[j] = (wv * 16 + j * 8) * 32;
  }

  f32x4 acc[4][2] = {};

#define S2_STAGE(slot, kp) do {                                   \
    const int su_ = (slot) * 4096, sf_ = (slot) * 2048;           \
    const int ko_ = (kp) * 32;                                    \
    gl16(gpA[0] + ko_, &sA[su_ + lbA[0]]);                        \
    gl16(gpA[1] + ko_, &sA[su_ + lbA[1]]);                        \
    gl16(gpB[0] + ko_, &sB[sf_ + lbB[0]]);                        \
    gl16(gpB[1] + ko_, &sB[sf_ + lbB[1]]);                        \
  } while (0)

#define S2_COMPUTE(slot) do {                                     \
    const int su_ = (slot) * 4096, sf_ = (slot) * 2048;           \
    const int fr_ = lane & 15, kb_ = lane >> 4;                   \
    bf16x8 a0 = RDB(sA, su_, wm + fr_, kb_);                      \
    bf16x8 a1 = RDB(sA, su_, wm + 16 + fr_, kb_);                 \
    bf16x8 a2 = RDB(sA, su_, wm + 32 + fr_, kb_);                 \
    bf16x8 a3 = RDB(sA, su_, wm + 48 + fr_, kb_);                 \
    bf16x8 b0 = RD8(sB, sf_, wn + fr_, kb_);                      \
    bf16x8 b1 = RD8(sB, sf_, wn + 16 + fr_, kb_);                 \
    acc[0][0] = mfma(a0, b0, acc[0][0]);                          \
    acc[1][0] = mfma(a1, b0, acc[1][0]);                          \
    acc[2][0] = mfma(a2, b0, acc[2][0]);                          \
    acc[3][0] = mfma(a3, b0, acc[3][0]);                          \
    acc[0][1] = mfma(a0, b1, acc[0][1]);                          \
    acc[1][1] = mfma(a1, b1, acc[1][1]);                          \
    acc[2][1] = mfma(a2, b1, acc[2][1]);                          \
    acc[3][1] = mfma(a3, b1, acc[3][1]);                          \
  } while (0)

  S2_STAGE(0, 0);
  S2_STAGE(1, 1);
  VMW(4);
  BAR();

#pragma unroll 1
  for (int l = 0; l < 32; ++l) {
    if (l + 2 < 32) S2_STAGE((l + 2) % 3, l + 2);
    SCHEDB();
    S2_COMPUTE(l % 3);
    SCHEDB();
    if (l + 2 < 32) { VMW(4); BAR(); }
    else if (l == 30) { VMW(0); BAR(); }
  }

  const int crow = (lane >> 4) << 2;
  const int ccol = lane & 15;
#pragma unroll
  for (int mi = 0; mi < 4; ++mi) {
#pragma unroll
    for (int ri = 0; ri < 4; ++ri) {
      const int lm = wm + mi * 16 + crow + ri;
      if (lm < rows) {
        const int tok = perm[r0 + lm];
        float* orow = out + (size_t)tok * DDIM + nt * 64 + wn;
#pragma unroll
        for (int nj = 0; nj < 2; ++nj) {
          atomicAdd(&orow[nj * 16 + ccol], acc[mi][nj][ri]);
        }
      }
    }
  }
}

// ---------------------------------------------------------------------------
extern "C" void kernel_launch(void* const* d_in, const int* in_sizes, int n_in,
                              void* d_out, int out_size, void* d_ws, size_t ws_size,
                              hipStream_t stream) {
  const float* x  = (const float*)d_in[0];
  const int* idx  = (const int*)d_in[1];
  const float* wg = (const float*)d_in[2];
  const float* wu = (const float*)d_in[3];
  const float* wd = (const float*)d_in[4];
  float* out = (float*)d_out;

  int* iws = (int*)d_ws;
  int* meta = iws;        // layout in moe_dispatch comment
  int* perm = iws + 128;  // 2048 ints
  u16* xbuf = (u16*)((char*)d_ws + 16384);              // 1024x768 bf16
  u16* hbuf = (u16*)((char*)d_ws + 16384 + (1 << 21));  // 2048x2048 bf16

  hipMemsetAsync(d_out, 0, (size_t)out_size * sizeof(float), stream);
  moe_cvtx<<<NTOK * DDIM / 2048, 256, 0, stream>>>(x, xbuf);
  moe_dispatch<<<1, 256, 0, stream>>>(idx, meta, perm);
  moe_stage1<<<MAXT1 * 32, 512, 0, stream>>>(xbuf, perm, meta, wg, wu, hbuf);
  moe_stage2<<<MAXT2 * 24, 256, 0, stream>>>(hbuf, perm, meta, wd, out);
}

// Round 17
// 82.377 us; speedup vs baseline: 1.3475x; 1.1057x over previous
//
#include <hip/hip_runtime.h>

// ---------------------------------------------------------------------------
// SwitchGLU MoE, round 17: stage1 at 3 blocks/CU (the one untested regime).
// Cross-round staging-rate table: rate is monotone in blocks/CU
// (1->2->3 : 2->4-5->8.8 TB/s), schedule flavor irrelevant. Stage1 here:
// 256 thr, BM=128, BN=64(G)+64(U), ring-2 LDS 48KB -> 3 blocks/CU, drain.
// Staged bytes 246->331MB (W-dup x2); breakeven rate 5.9 TB/s.
// Stage2 / cvtx / dispatch byte-identical to R13 (best: 88.8us). No swizzles.
// ---------------------------------------------------------------------------

typedef unsigned short u16;
typedef unsigned int   u32;
typedef u16    u16x8 __attribute__((ext_vector_type(8)));
typedef __bf16 bf16x8 __attribute__((ext_vector_type(8)));
typedef float  f32x4 __attribute__((ext_vector_type(4)));

#define NE   8
#define DDIM 768
#define HDIM 2048
#define NTOT 2048
#define NTOK 1024
#define MAXT2 24   // 128-row tiles

__device__ __forceinline__ u16 f2bf(float f) {
  return (u16)((__builtin_bit_cast(u32, f) + 0x8000u) >> 16);
}
__device__ __forceinline__ bf16x8 cvt8(float4 a, float4 b) {
  bf16x8 r;
  r[0] = (__bf16)a.x; r[1] = (__bf16)a.y; r[2] = (__bf16)a.z; r[3] = (__bf16)a.w;
  r[4] = (__bf16)b.x; r[5] = (__bf16)b.y; r[6] = (__bf16)b.z; r[7] = (__bf16)b.w;
  return r;
}
__device__ __forceinline__ f32x4 mfma(bf16x8 a, bf16x8 b, f32x4 c) {
  return __builtin_amdgcn_mfma_f32_16x16x32_bf16(a, b, c, 0, 0, 0);
}
__device__ __forceinline__ void gl16(const void* g, void* l) {
  __builtin_amdgcn_global_load_lds(
      (const __attribute__((address_space(1))) void*)g,
      (__attribute__((address_space(3))) void*)l, 16, 0, 0);
}
#define SCHEDB() __builtin_amdgcn_sched_barrier(0)
#define BAR()    __builtin_amdgcn_s_barrier()
#define VMW(n)   asm volatile("s_waitcnt vmcnt(" #n ")" ::: "memory")
#define PSYNC()  do { SCHEDB(); \
    asm volatile("s_waitcnt vmcnt(0) lgkmcnt(0)" ::: "memory"); \
    BAR(); SCHEDB(); } while (0)

// fp32 tile frag read (R5-verified pair): rows of 32 floats, 16B chunk ^= r&7
#define RD8(arr, o_, r_, kb_) cvt8(                                              \
    *(const float4*)&(arr)[(o_) + (r_) * 32 + ((((kb_)*2    ) ^ ((r_)&7)) << 2)], \
    *(const float4*)&(arr)[(o_) + (r_) * 32 + ((((kb_)*2 + 1) ^ ((r_)&7)) << 2)])
// bf16 tile frag read (R5-verified pair): rows of 32 u16, 16B chunk ^= (r>>1)&3
#define RDB(arr, o_, r_, kb_) __builtin_bit_cast(bf16x8,                         \
    *(const u16x8*)&(arr)[(o_) + (r_) * 32 + (((kb_) ^ (((r_)>>1)&3)) << 3)])

// ---------------------------------------------------------------------------
__global__ __launch_bounds__(256) void moe_cvtx(const float* __restrict__ x,
                                                u16* __restrict__ xb) {
  const int i = (blockIdx.x * 256 + threadIdx.x) * 8;
  const float4 f0 = *(const float4*)(x + i);
  const float4 f1 = *(const float4*)(x + i + 4);
  *(uint4*)(xb + i) = __builtin_bit_cast(uint4, cvt8(f0, f1));
}

// ---------------------------------------------------------------------------
// Dispatch: expert bucketing + 128-row tile table.
// meta: [0..8] offs, [14] ntiles128, [48+t] e128, [80+t] r0_128 (t<24).
// ---------------------------------------------------------------------------
__global__ void moe_dispatch(const int* __restrict__ idx,
                             int* __restrict__ meta, int* __restrict__ perm) {
  __shared__ int s_cnt[NE];
  __shared__ int s_off[NE + 1];
  __shared__ int s_cur[NE];
  const int tid = threadIdx.x;
  if (tid < NE) { s_cnt[tid] = 0; s_cur[tid] = 0; }
  __syncthreads();
  for (int n = tid; n < NTOT; n += 256) atomicAdd(&s_cnt[idx[n]], 1);
  __syncthreads();
  if (tid == 0) {
    int a = 0;
    for (int e = 0; e < NE; ++e) { s_off[e] = a; a += s_cnt[e]; }
    s_off[NE] = a;
  }
  __syncthreads();
  for (int n = tid; n < NTOT; n += 256) {
    const int e = idx[n];
    perm[s_off[e] + atomicAdd(&s_cur[e], 1)] = n;
  }
  if (tid == 0) {
    int t2 = 0;
    for (int e = 0; e < NE; ++e) {
      for (int r0 = s_off[e]; r0 < s_off[e + 1]; r0 += 128) {
        meta[48 + t2] = e; meta[80 + t2] = r0; ++t2;
      }
    }
    meta[14] = t2;
  }
  if (tid < NE + 1) meta[tid] = s_off[tid];
}

// ---------------------------------------------------------------------------
// Stage 1: h = silu(X Wg^T) * (X Wu^T).  BM=128, BN=64(G)+64(U), BK=32.
// grid = MAXT2*32 (tile t, H-strip nt). 256 thr = 4 waves (2M x 2N);
// wave = 64M x 32N of both. Ring-2 LDS 48KB -> 3 blocks/CU (12 waves/CU).
// 6 gl16/thread/step, drain per step.
// ---------------------------------------------------------------------------
__global__ __launch_bounds__(256, 3) void moe_stage1(
    const u16* __restrict__ xb, const int* __restrict__ perm,
    const int* __restrict__ meta, const float* __restrict__ wg,
    const float* __restrict__ wu, u16* __restrict__ hbuf) {
  const int t = blockIdx.x >> 5;
  if (t >= meta[14]) return;
  const int nt = blockIdx.x & 31;  // H cols nt*64
  const int e = meta[48 + t];
  const int r0 = meta[80 + t];
  const int rows = min(128, meta[e + 1] - r0);

  __shared__ __align__(16) u16   sX[2 * 128 * 32];  // 8KB/buf
  __shared__ __align__(16) float sG[2 * 64 * 32];   // 8KB/buf
  __shared__ __align__(16) float sU[2 * 64 * 32];   // 8KB/buf

  const int tid = threadIdx.x;
  const int lane = tid & 63;
  const int wv = tid >> 6;
  const int wm = (wv >> 1) * 64;  // 0,64
  const int wn = (wv & 1) * 32;   // 0,32

  // X staging (bf16): 2 gl16/thread; row r, chunk (lane&3)^((r>>1)&3)
  const u16* gpX[2];
  int lbX[2];
#pragma unroll
  for (int j = 0; j < 2; ++j) {
    const int r = wv * 32 + j * 16 + (lane >> 2);
    const int tok = perm[r0 + min(r, rows - 1)] >> 1;  // TOPK=2
    gpX[j] = xb + (size_t)tok * DDIM + (((lane & 3) ^ ((r >> 1) & 3)) << 3);
    lbX[j] = (wv * 32 + j * 16) * 32;
  }
  // W staging (fp32): 2 gl16/thread each; row r, chunk (lane&7)^(r&7)
  const float* gpG[2];
  const float* gpU[2];
  int lbW[2];
#pragma unroll
  for (int j = 0; j < 2; ++j) {
    const int r = wv * 16 + j * 8 + (lane >> 3);
    const size_t row = (size_t)e * HDIM + nt * 64 + r;
    gpG[j] = wg + row * DDIM + (((lane & 7) ^ (r & 7)) << 2);
    gpU[j] = wu + row * DDIM + (((lane & 7) ^ (r & 7)) << 2);
    lbW[j] = (wv * 16 + j * 8) * 32;
  }

  f32x4 aG[4][2] = {};
  f32x4 aU[4][2] = {};

#define S1_STAGE(b, kt) do {                                      \
    const int ko_ = (kt) * 32;                                    \
    gl16(gpX[0] + ko_, &sX[(b) * 4096 + lbX[0]]);                 \
    gl16(gpX[1] + ko_, &sX[(b) * 4096 + lbX[1]]);                 \
    gl16(gpG[0] + ko_, &sG[(b) * 2048 + lbW[0]]);                 \
    gl16(gpG[1] + ko_, &sG[(b) * 2048 + lbW[1]]);                 \
    gl16(gpU[0] + ko_, &sU[(b) * 2048 + lbW[0]]);                 \
    gl16(gpU[1] + ko_, &sU[(b) * 2048 + lbW[1]]);                 \
  } while (0)

#define S1_COMPUTE(b) do {                                        \
    const int fr_ = lane & 15, kb_ = lane >> 4;                   \
    bf16x8 a0 = RDB(sX, (b) * 4096, wm + fr_, kb_);               \
    bf16x8 a1 = RDB(sX, (b) * 4096, wm + 16 + fr_, kb_);          \
    bf16x8 a2 = RDB(sX, (b) * 4096, wm + 32 + fr_, kb_);          \
    bf16x8 a3 = RDB(sX, (b) * 4096, wm + 48 + fr_, kb_);          \
    bf16x8 g0 = RD8(sG, (b) * 2048, wn + fr_, kb_);               \
    bf16x8 g1 = RD8(sG, (b) * 2048, wn + 16 + fr_, kb_);          \
    bf16x8 u0 = RD8(sU, (b) * 2048, wn + fr_, kb_);               \
    bf16x8 u1 = RD8(sU, (b) * 2048, wn + 16 + fr_, kb_);          \
    aG[0][0] = mfma(a0, g0, aG[0][0]);                            \
    aG[1][0] = mfma(a1, g0, aG[1][0]);                            \
    aG[2][0] = mfma(a2, g0, aG[2][0]);                            \
    aG[3][0] = mfma(a3, g0, aG[3][0]);                            \
    aG[0][1] = mfma(a0, g1, aG[0][1]);                            \
    aG[1][1] = mfma(a1, g1, aG[1][1]);                            \
    aG[2][1] = mfma(a2, g1, aG[2][1]);                            \
    aG[3][1] = mfma(a3, g1, aG[3][1]);                            \
    aU[0][0] = mfma(a0, u0, aU[0][0]);                            \
    aU[1][0] = mfma(a1, u0, aU[1][0]);                            \
    aU[2][0] = mfma(a2, u0, aU[2][0]);                            \
    aU[3][0] = mfma(a3, u0, aU[3][0]);                            \
    aU[0][1] = mfma(a0, u1, aU[0][1]);                            \
    aU[1][1] = mfma(a1, u1, aU[1][1]);                            \
    aU[2][1] = mfma(a2, u1, aU[2][1]);                            \
    aU[3][1] = mfma(a3, u1, aU[3][1]);                            \
  } while (0)

  S1_STAGE(0, 0);
  PSYNC();
#pragma unroll 1
  for (int kt = 0; kt < 24; ++kt) {
    const int cb = kt & 1;
    if (kt + 1 < 24) S1_STAGE(cb ^ 1, kt + 1);
    SCHEDB();
    S1_COMPUTE(cb);
    PSYNC();
  }

  // epilogue: C/D layout col=lane&15, row=(lane>>4)*4+reg
  const int crow = (lane >> 4) << 2;
  const int ccol = lane & 15;
#pragma unroll
  for (int mi = 0; mi < 4; ++mi) {
#pragma unroll
    for (int ri = 0; ri < 4; ++ri) {
      const int lm = wm + mi * 16 + crow + ri;
      if (lm < rows) {
        u16* hb = hbuf + (size_t)(r0 + lm) * HDIM + nt * 64 + wn;
#pragma unroll
        for (int nj = 0; nj < 2; ++nj) {
          const float gv = aG[mi][nj][ri];
          const float uv = aU[mi][nj][ri];
          const float h = gv / (1.0f + __expf(-gv)) * uv;
          hb[nj * 16 + ccol] = f2bf(h);
        }
      }
    }
  }
}

// ---------------------------------------------------------------------------
// Stage 2 (byte-identical to R13): out += h Wd^T. BM=128/BN=64/BK=32/splitK=2.
// Ring-3 LDS 48KB (3 blocks/CU), counted vmcnt(4).
// ---------------------------------------------------------------------------
__global__ __launch_bounds__(256, 3) void moe_stage2(
    const u16* __restrict__ hbuf, const int* __restrict__ perm,
    const int* __restrict__ meta, const float* __restrict__ wd,
    float* __restrict__ out) {
  const int t = blockIdx.x / 24;
  if (t >= meta[14]) return;
  const int rem = blockIdx.x - t * 24;
  const int ks = rem / 12;
  const int nt = rem - ks * 12;
  const int e = meta[48 + t];
  const int r0 = meta[80 + t];
  const int rows = min(128, meta[e + 1] - r0);

  __shared__ __align__(16) u16   sA[3 * 128 * 32];
  __shared__ __align__(16) float sB[3 * 64 * 32];

  const int tid = threadIdx.x;
  const int lane = tid & 63;
  const int wv = tid >> 6;
  const int wm = (wv >> 1) * 64;
  const int wn = (wv & 1) * 32;

  const u16* gpA[2];
  int lbA[2];
#pragma unroll
  for (int j = 0; j < 2; ++j) {
    const int r = wv * 32 + j * 16 + (lane >> 2);
    gpA[j] = hbuf + (size_t)(r0 + min(r, rows - 1)) * HDIM + ks * 1024 +
             (((lane & 3) ^ ((r >> 1) & 3)) << 3);
    lbA[j] = (wv * 32 + j * 16) * 32;
  }
  const float* gpB[2];
  int lbB[2];
#pragma unroll
  for (int j = 0; j < 2; ++j) {
    const int r = wv * 16 + j * 8 + (lane >> 3);
    gpB[j] = wd + ((size_t)e * DDIM + nt * 64 + r) * HDIM + ks * 1024 +
             (((lane & 7) ^ (r & 7)) << 2);
    lbB[j] = (wv * 16 + j * 8) * 32;
  }

  f32x4 acc[4][2] = {};

#define S2_STAGE(slot, kp) do {                                   \
    const int su_ = (slot) * 4096, sf_ = (slot) * 2048;           \
    const int ko_ = (kp) * 32;                                    \
    gl16(gpA[0] + ko_, &sA[su_ + lbA[0]]);                        \
    gl16(gpA[1] + ko_, &sA[su_ + lbA[1]]);                        \
    gl16(gpB[0] + ko_, &sB[sf_ + lbB[0]]);                        \
    gl16(gpB[1] + ko_, &sB[sf_ + lbB[1]]);                        \
  } while (0)

#define S2_COMPUTE(slot) do {                                     \
    const int su_ = (slot) * 4096, sf_ = (slot) * 2048;           \
    const int fr_ = lane & 15, kb_ = lane >> 4;                   \
    bf16x8 a0 = RDB(sA, su_, wm + fr_, kb_);                      \
    bf16x8 a1 = RDB(sA, su_, wm + 16 + fr_, kb_);                 \
    bf16x8 a2 = RDB(sA, su_, wm + 32 + fr_, kb_);                 \
    bf16x8 a3 = RDB(sA, su_, wm + 48 + fr_, kb_);                 \
    bf16x8 b0 = RD8(sB, sf_, wn + fr_, kb_);                      \
    bf16x8 b1 = RD8(sB, sf_, wn + 16 + fr_, kb_);                 \
    acc[0][0] = mfma(a0, b0, acc[0][0]);                          \
    acc[1][0] = mfma(a1, b0, acc[1][0]);                          \
    acc[2][0] = mfma(a2, b0, acc[2][0]);                          \
    acc[3][0] = mfma(a3, b0, acc[3][0]);                          \
    acc[0][1] = mfma(a0, b1, acc[0][1]);                          \
    acc[1][1] = mfma(a1, b1, acc[1][1]);                          \
    acc[2][1] = mfma(a2, b1, acc[2][1]);                          \
    acc[3][1] = mfma(a3, b1, acc[3][1]);                          \
  } while (0)

  S2_STAGE(0, 0);
  S2_STAGE(1, 1);
  VMW(4);
  BAR();

#pragma unroll 1
  for (int l = 0; l < 32; ++l) {
    if (l + 2 < 32) S2_STAGE((l + 2) % 3, l + 2);
    SCHEDB();
    S2_COMPUTE(l % 3);
    SCHEDB();
    if (l + 2 < 32) { VMW(4); BAR(); }
    else if (l == 30) { VMW(0); BAR(); }
  }

  const int crow = (lane >> 4) << 2;
  const int ccol = lane & 15;
#pragma unroll
  for (int mi = 0; mi < 4; ++mi) {
#pragma unroll
    for (int ri = 0; ri < 4; ++ri) {
      const int lm = wm + mi * 16 + crow + ri;
      if (lm < rows) {
        const int tok = perm[r0 + lm];
        float* orow = out + (size_t)tok * DDIM + nt * 64 + wn;
#pragma unroll
        for (int nj = 0; nj < 2; ++nj) {
          atomicAdd(&orow[nj * 16 + ccol], acc[mi][nj][ri]);
        }
      }
    }
  }
}

// ---------------------------------------------------------------------------
extern "C" void kernel_launch(void* const* d_in, const int* in_sizes, int n_in,
                              void* d_out, int out_size, void* d_ws, size_t ws_size,
                              hipStream_t stream) {
  const float* x  = (const float*)d_in[0];
  const int* idx  = (const int*)d_in[1];
  const float* wg = (const float*)d_in[2];
  const float* wu = (const float*)d_in[3];
  const float* wd = (const float*)d_in[4];
  float* out = (float*)d_out;

  int* iws = (int*)d_ws;
  int* meta = iws;        // layout in moe_dispatch comment
  int* perm = iws + 128;  // 2048 ints
  u16* xbuf = (u16*)((char*)d_ws + 16384);              // 1024x768 bf16
  u16* hbuf = (u16*)((char*)d_ws + 16384 + (1 << 21));  // 2048x2048 bf16

  hipMemsetAsync(d_out, 0, (size_t)out_size * sizeof(float), stream);
  moe_cvtx<<<NTOK * DDIM / 2048, 256, 0, stream>>>(x, xbuf);
  moe_dispatch<<<1, 256, 0, stream>>>(idx, meta, perm);
  moe_stage1<<<MAXT2 * 32, 256, 0, stream>>>(xbuf, perm, meta, wg, wu, hbuf);
  moe_stage2<<<MAXT2 * 24, 256, 0, stream>>>(hbuf, perm, meta, wd, out);
}